// Round 21
// baseline (337.836 us; speedup 1.0000x reference)
//
#include <hip/hip_runtime.h>

typedef __bf16 bf16_t;
typedef __bf16 bf16x8 __attribute__((ext_vector_type(8)));
typedef float f32x4 __attribute__((ext_vector_type(4)));

#define MFMA(a, b, c) __builtin_amdgcn_mfma_f32_16x16x32_bf16((a), (b), (c), 0, 0, 0)

#define E_ROWS 640000
#define BM 128  // rows per block: 8 waves x 16

static __device__ __forceinline__ bf16x8 cvt8(float4 a, float4 b) {
  bf16x8 r;
  r[0] = (bf16_t)a.x; r[1] = (bf16_t)a.y; r[2] = (bf16_t)a.z; r[3] = (bf16_t)a.w;
  r[4] = (bf16_t)b.x; r[5] = (bf16_t)b.y; r[6] = (bf16_t)b.z; r[7] = (bf16_t)b.w;
  return r;
}

static __device__ __forceinline__ unsigned int pk2(float a, float b) {
  unsigned short ua = __builtin_bit_cast(unsigned short, (bf16_t)a);
  unsigned short ub = __builtin_bit_cast(unsigned short, (bf16_t)b);
  return ((unsigned int)ub << 16) | ua;
}

static __device__ __forceinline__ void gload_lds16(const void* g, void* l) {
  __builtin_amdgcn_global_load_lds(
      (const __attribute__((address_space(1))) unsigned int*)g,
      (__attribute__((address_space(3))) unsigned int*)l, 16, 0, 0);
}

// Fragment-ordered weights in ws (table chunk = frag*64 + lane, 16B each):
//   Wm1: frags 0..63 (chunks 0..4095)    Wm2: 64..95 (4096..6143)
//   Wu1: 96..159 (6144..10239)           Wu2: 160..191 (10240..12287)
// chunk holds 8 bf16: W[k][n], k = 32*ks + 8*(lane>>4) + j, n = 16*nb + (lane&15).
__global__ __launch_bounds__(256) void prep_weights(
    const float* __restrict__ Wm1, const float* __restrict__ Wm2,
    const float* __restrict__ Wu1, const float* __restrict__ Wu2,
    bf16_t* __restrict__ wt) {
  int c = blockIdx.x * 256 + threadIdx.x;
  if (c >= 12288) return;
  int lane = c & 63, f = c >> 6;
  const float* W; int base;
  if (f < 64)       { W = Wm1; base = 0;   }
  else if (f < 96)  { W = Wm2; base = 64;  }
  else if (f < 160) { W = Wu1; base = 96;  }
  else              { W = Wu2; base = 160; }
  int fl = f - base;
  int ks = fl >> 3, nb = fl & 7;
  int k0 = 32 * ks + 8 * (lane >> 4);
  int n  = 16 * nb + (lane & 15);
  bf16x8 v;
  #pragma unroll
  for (int j = 0; j < 8; ++j) v[j] = (bf16_t)W[(size_t)(k0 + j) * 128 + n];
  ((bf16x8*)wt)[c] = v;
}

// stage 64KB (8 iters) into W[0..64K) / 32KB (4 iters) into dst, 512 threads
#define STAGE64(tc0) { \
  _Pragma("unroll") \
  for (int i_ = 0; i_ < 8; ++i_) \
    gload_lds16((const char*)wt + ((size_t)((tc0) + i_ * 512 + tid)) * 16, \
                smem + (i_ * 512 + tid) * 16); }
#define STAGE32(tc0, dst) { \
  _Pragma("unroll") \
  for (int i_ = 0; i_ < 4; ++i_) \
    gload_lds16((const char*)wt + ((size_t)((tc0) + i_ * 512 + tid)) * 16, \
                (dst) + (i_ * 512 + tid) * 16); }

// 8 W-frags (one ks) from a 32K region: per-lane 16B ds_read_b128
#define LDW8(s, base, fl0) \
  s##0 = *(const bf16x8*)((base) + ((fl0) + 0) * 1024 + lane * 16); \
  s##1 = *(const bf16x8*)((base) + ((fl0) + 1) * 1024 + lane * 16); \
  s##2 = *(const bf16x8*)((base) + ((fl0) + 2) * 1024 + lane * 16); \
  s##3 = *(const bf16x8*)((base) + ((fl0) + 3) * 1024 + lane * 16); \
  s##4 = *(const bf16x8*)((base) + ((fl0) + 4) * 1024 + lane * 16); \
  s##5 = *(const bf16x8*)((base) + ((fl0) + 5) * 1024 + lane * 16); \
  s##6 = *(const bf16x8*)((base) + ((fl0) + 6) * 1024 + lane * 16); \
  s##7 = *(const bf16x8*)((base) + ((fl0) + 7) * 1024 + lane * 16);

// one mt: 8 MFMA per round
#define ROUND(s, x0) \
  acc0 = MFMA(s##0, x0, acc0); acc1 = MFMA(s##1, x0, acc1); \
  acc2 = MFMA(s##2, x0, acc2); acc3 = MFMA(s##3, x0, acc3); \
  acc4 = MFMA(s##4, x0, acc4); acc5 = MFMA(s##5, x0, acc5); \
  acc6 = MFMA(s##6, x0, acc6); acc7 = MFMA(s##7, x0, acc7);

#define ACCINIT(bp) { const float* bp_ = (bp) + g * 4; float4 q; \
  q = *(const float4*)(bp_ +   0); acc0 = (f32x4){q.x,q.y,q.z,q.w}; \
  q = *(const float4*)(bp_ +  16); acc1 = (f32x4){q.x,q.y,q.z,q.w}; \
  q = *(const float4*)(bp_ +  32); acc2 = (f32x4){q.x,q.y,q.z,q.w}; \
  q = *(const float4*)(bp_ +  48); acc3 = (f32x4){q.x,q.y,q.z,q.w}; \
  q = *(const float4*)(bp_ +  64); acc4 = (f32x4){q.x,q.y,q.z,q.w}; \
  q = *(const float4*)(bp_ +  80); acc5 = (f32x4){q.x,q.y,q.z,q.w}; \
  q = *(const float4*)(bp_ +  96); acc6 = (f32x4){q.x,q.y,q.z,q.w}; \
  q = *(const float4*)(bp_ + 112); acc7 = (f32x4){q.x,q.y,q.z,q.w}; }

// repack one acc (16 rows): D holds h[rowbase+c][16nb+4g+e]; scatter so a 16B
// read at (ks*64+lane)*16 within myrep yields the next GEMM's B-frag.
#define RPK(av, nb, R) { \
  f32x4 v = av; \
  float e0 = v[0], e1 = v[1], e2 = v[2], e3 = v[3]; \
  if (R) { e0 = fmaxf(e0, 0.f); e1 = fmaxf(e1, 0.f); \
           e2 = fmaxf(e2, 0.f); e3 = fmaxf(e3, 0.f); } \
  uint2 w; w.x = pk2(e0, e1); w.y = pk2(e2, e3); \
  int dl = c + 16 * (2 * ((nb) & 1) + (g >> 1)); \
  *(uint2*)((myrep) + (((nb) >> 1) * 64 + dl) * 16 + (g & 1) * 8) = w; }

#define WAITLDS asm volatile("s_waitcnt lgkmcnt(0)" ::: "memory");
#define VMCNT0  asm volatile("s_waitcnt vmcnt(0)" ::: "memory");

// full repack into region rbase (wave-private 4KB each), read back into x0..x3
#define REPACK(R, rbase) { \
  char* myrep = (rbase) + wave * 4096; \
  RPK(acc0, 0, R) RPK(acc1, 1, R) RPK(acc2, 2, R) RPK(acc3, 3, R) \
  RPK(acc4, 4, R) RPK(acc5, 5, R) RPK(acc6, 6, R) RPK(acc7, 7, R) \
  WAITLDS \
  x0 = *(const bf16x8*)(myrep + (0 * 64 + lane) * 16); \
  x1 = *(const bf16x8*)(myrep + (1 * 64 + lane) * 16); \
  x2 = *(const bf16x8*)(myrep + (2 * 64 + lane) * 16); \
  x3 = *(const bf16x8*)(myrep + (3 * 64 + lane) * 16); \
  WAITLDS }

#define LOADX(d0, basep, kk) { \
  float4 a0 = *(const float4*)((basep) + r0 + (kk) * 32); \
  float4 a1 = *(const float4*)((basep) + r0 + (kk) * 32 + 4); \
  d0 = cvt8(a0, a1); }

#define ST(av, nb) { f32x4 v = av; \
  *(float4*)(out + (rowbase + c) * 128 + (nb) * 16 + g * 4) = \
      (float4){v[0], v[1], v[2], v[3]}; }

// 512 thr, 8 waves x 16 rows = 128 rows/block, grid 5000. LDS 64KB total:
// W lower [0,32K) / upper [32K,64K); repack ALIASED into the just-consumed
// half (8 waves x 4KB = 32K exactly). 2 blocks/CU (128KB LDS, 16 waves).
// declared-512 @ 64KB -> HW cap 128 unified regs/wave; 1-mt live set
// (acc 32 + hs 16 + x 16 + wa 32 + addr ~20 = ~116) FITS -> no spill
// (R19's spill was the 2-mt live set 168 under the same cap).
__global__ __launch_bounds__(512) void fused_mp(
    const float* __restrict__ hself, const float* __restrict__ hother,
    const bf16_t* __restrict__ wt,
    const float* __restrict__ bm1, const float* __restrict__ bm2,
    const float* __restrict__ bu1, const float* __restrict__ bu2,
    float* __restrict__ out) {
  __shared__ char smem[65536];

  const int tid = threadIdx.x;
  const int lane = tid & 63;
  const int wave = tid >> 6;
  const int c = lane & 15;
  const int g = lane >> 4;

  char* LO = smem;            // lower 32K
  char* UP = smem + 32768;    // upper 32K

  const size_t rowbase = (size_t)blockIdx.x * BM + wave * 16;
  const size_t r0 = (rowbase + c) * 128 + g * 8;

  // ---- prologue: Wm1 DMA (64K), x loads ----
  bf16x8 hs0, hs1, hs2, hs3;
  bf16x8 x0, x1, x2, x3;
  STAGE64(0)
  __builtin_amdgcn_sched_barrier(0);
  LOADX(hs0, hself, 0)
  LOADX(hs1, hself, 1)
  LOADX(hs2, hself, 2)
  LOADX(hs3, hself, 3)
  LOADX(x0, hother, 0)
  LOADX(x1, hother, 1)
  LOADX(x2, hother, 2)
  LOADX(x3, hother, 3)
  VMCNT0
  __syncthreads();  // B0: Wm1 staged

  f32x4 acc0, acc1, acc2, acc3, acc4, acc5, acc6, acc7;
  bf16x8 wa0, wa1, wa2, wa3, wa4, wa5, wa6, wa7;

  // ============ GEMM1: h1^T = Wm1^T [hs|ho]^T  (+bm1, relu) ============
  ACCINIT(bm1)
  LDW8(wa, LO, 0)   ROUND(wa, hs0)
  LDW8(wa, LO, 8)   ROUND(wa, hs1)
  LDW8(wa, LO, 16)  ROUND(wa, hs2)
  LDW8(wa, LO, 24)  ROUND(wa, hs3)
  LDW8(wa, UP, 0)   ROUND(wa, x0)
  LDW8(wa, UP, 8)   ROUND(wa, x1)
  LDW8(wa, UP, 16)  ROUND(wa, x2)
  LDW8(wa, UP, 24)  ROUND(wa, x3)
  __syncthreads();  // B1: Wm1 fully consumed

  // phase2: Wm2 -> UP (async) | repack h1 -> LO
  STAGE32(4096, UP)
  REPACK(true, LO)
  VMCNT0
  __syncthreads();  // B2: Wm2 staged; h1 frags in regs

  // ============ GEMM2: msg^T = Wm2^T h1^T  (+bm2) ============
  ACCINIT(bm2)
  LDW8(wa, UP, 0)   ROUND(wa, x0)
  LDW8(wa, UP, 8)   ROUND(wa, x1)
  LDW8(wa, UP, 16)  ROUND(wa, x2)
  LDW8(wa, UP, 24)  ROUND(wa, x3)
  __syncthreads();  // B3: Wm2 consumed; LO (h1 repack) long free

  // phase4: Wu1-lo (hs part) -> LO (async) | repack msg -> UP
  STAGE32(6144, LO)
  REPACK(false, UP)
  VMCNT0
  __syncthreads();  // B4: Wu1-lo staged; msg frags in regs

  // ============ GEMM3: h2^T = Wu1^T [hs|msg]^T  (+bu1, relu) ============
  // phase5: Wu1-hi (msg part) -> UP flies under GEMM3a
  STAGE32(8192, UP)
  ACCINIT(bu1)
  LDW8(wa, LO, 0)   ROUND(wa, hs0)
  LDW8(wa, LO, 8)   ROUND(wa, hs1)
  LDW8(wa, LO, 16)  ROUND(wa, hs2)
  LDW8(wa, LO, 24)  ROUND(wa, hs3)
  VMCNT0
  __syncthreads();  // B5: Wu1-hi staged
  LDW8(wa, UP, 0)   ROUND(wa, x0)
  LDW8(wa, UP, 8)   ROUND(wa, x1)
  LDW8(wa, UP, 16)  ROUND(wa, x2)
  LDW8(wa, UP, 24)  ROUND(wa, x3)
  __syncthreads();  // B6: Wu1 fully consumed

  // phase6: Wu2 -> LO (async) | repack h2 -> UP
  STAGE32(10240, LO)
  REPACK(true, UP)
  VMCNT0
  __syncthreads();  // B7: Wu2 staged; h2 frags in regs

  // ============ GEMM4: out^T = Wu2^T h2^T  (+bu2) ============
  ACCINIT(bu2)
  LDW8(wa, LO, 0)   ROUND(wa, x0)
  LDW8(wa, LO, 8)   ROUND(wa, x1)
  LDW8(wa, LO, 16)  ROUND(wa, x2)
  LDW8(wa, LO, 24)  ROUND(wa, x3)

  ST(acc0, 0) ST(acc1, 1) ST(acc2, 2) ST(acc3, 3)
  ST(acc4, 4) ST(acc5, 5) ST(acc6, 6) ST(acc7, 7)
}

extern "C" void kernel_launch(void* const* d_in, const int* in_sizes, int n_in,
                              void* d_out, int out_size, void* d_ws, size_t ws_size,
                              hipStream_t stream) {
  const float* hself  = (const float*)d_in[0];
  const float* hother = (const float*)d_in[1];
  const float* Wm1 = (const float*)d_in[2];
  const float* bm1 = (const float*)d_in[3];
  const float* Wm2 = (const float*)d_in[4];
  const float* bm2 = (const float*)d_in[5];
  const float* Wu1 = (const float*)d_in[6];
  const float* bu1 = (const float*)d_in[7];
  const float* Wu2 = (const float*)d_in[8];
  const float* bu2 = (const float*)d_in[9];
  float* out = (float*)d_out;
  bf16_t* wt = (bf16_t*)d_ws;  // 196608 B of fragment-ordered bf16 weights

  prep_weights<<<48, 256, 0, stream>>>(Wm1, Wm2, Wu1, Wu2, wt);
  fused_mp<<<E_ROWS / BM, 512, 0, stream>>>(hself, hother, wt,
                                            bm1, bm2, bu1, bu2, out);
}